// Round 16
// baseline (234.429 us; speedup 1.0000x reference)
//
#include <hip/hip_runtime.h>
#include <hip/hip_bf16.h>

#define BS   2
#define T    3
#define CCH  256
#define HH   48
#define WW   48
#define NH   8
#define NP   4
#define NL   3
#define DH   32
#define HWP  (HH*WW)     // 2304
#define LQ   (T*HWP)     // 6912
#define NIMG (BS*T)      // 6

typedef short v8s __attribute__((ext_vector_type(8)));
typedef float v4f __attribute__((ext_vector_type(4)));
typedef float v2f __attribute__((ext_vector_type(2)));
typedef unsigned int v2u __attribute__((ext_vector_type(2)));
typedef unsigned int v4u __attribute__((ext_vector_type(4)));

__device__ __forceinline__ unsigned short f2b(float f) {
    unsigned u = __float_as_uint(f);
    return (unsigned short)((u + 0x7FFFu + ((u >> 16) & 1u)) >> 16);
}

#define GLOAD_LDS16(gp, lp) \
    __builtin_amdgcn_global_load_lds((const __attribute__((address_space(1))) unsigned int*)(const void*)(gp), \
                                     (__attribute__((address_space(3))) unsigned int*)(void*)(lp), 16, 0, 0)

// LDS layout (bytes): slab @0 (288*128=36864), zero-row @36864. Total 36992.
// Ledger: r6 single-buffer A serialized tap loads (72->118). r8 reg-prefetch
// ds_write on barrier path (74->87). r10 wide conv tile blew VGPR (74->100).
// r12 2-lane sampler blew VGPR (sample 25->76). r14/r15 XCD swizzles: FETCH
// 3x down, balanced. r15 analysis: phase-0 ~78% LDS-read-pipe-bound
// (8 waves x 576 ds_read_b128 x 12cy vs 71K cyc/round), VMEM idle.
// r16: A-operands via fragment-major GLOBAL loads (coalesced 1KB/wave from
// L2) -> LDS traffic halves, A-dbuf + per-tap barriers deleted (76 -> 8).
#define LDS_ZROW  36864
#define LDS_TOTAL 36992

// m204 bijective chunked swizzle within a range of n blocks.
__device__ __forceinline__ int xcd_swz(int p, int n) {
    int q = n >> 3, r = n & 7;
    int xcd = p & 7, j = p >> 3;
    return (xcd < r ? xcd * (q + 1) : r * (q + 1) + (xcd - r) * q) + j;
}

// ---------------------------------------------------------------------------
// Fused prep kernel. Weight transform now writes FRAGMENT-MAJOR layout:
// WbF[k][chunk][ob][kk][lane][8 bf16]  (ob = oc/16, lane = g*16 + oc%16,
// element j = ic%8, kk = (ic%64)/32, g = (ic%32)/8, chunk = ic/64) so one
// wave A-fragment load = one coalesced 1KB global_load_dwordx4.
// ---------------------------------------------------------------------------
#define NB_FLOW 18
#define NB_WCVT 800
#define NB_TCVT 6912
#define WP0 (256*256)
#define WP1 (288*256)

__device__ __forceinline__ void wfrag_store(
    unsigned short* dst, int Mp, int oc, int ic, int k, float v)
{
    int c = ic >> 6, kk = (ic >> 5) & 1, g = (ic >> 3) & 3, j8 = ic & 7;
    int rowl = oc & 15, ob = oc >> 4;
    int lane = (g << 4) | rowl;
    size_t idx = ((((size_t)(k * 4 + c) * (Mp >> 4) + ob) * 2 + kk) * 64 + lane) * 8 + j8;
    dst[idx] = f2b(v);
}

__global__ __launch_bounds__(256) void prep_kernel(
    const float* __restrict__ ff, const float* __restrict__ fb,
    float* __restrict__ addb,
    const float* __restrict__ w_val, const float* __restrict__ w_off,
    const float* __restrict__ w_attn, const float* __restrict__ w_out,
    unsigned short* __restrict__ Wb_val, unsigned short* __restrict__ Wb_oa,
    unsigned short* __restrict__ Wb_out,
    const float* __restrict__ inputf, const float* __restrict__ query,
    unsigned short* __restrict__ inb_v, unsigned short* __restrict__ inb_q)
{
    __shared__ float lds[32][33];
    const int b = blockIdx.x;
    const int tid = threadIdx.x;

    if (b < NB_FLOW) {
        int idx = b * 256 + tid;
        int n = idx / HWP, pix = idx % HWP;
        int y = pix / WW, x = pix % WW;

        auto F = [&](const float* base, int i, int c, int p) {
            return base[n * (2*2*HWP) + i * (2*HWP) + c * HWP + p];
        };

        float f01x = F(ff,0,0,pix), f01y = F(ff,0,1,pix);
        float f12x = F(ff,1,0,pix), f12y = F(ff,1,1,pix);
        float b10x = F(fb,0,0,pix), b10y = F(fb,0,1,pix);
        float b21x = F(fb,1,0,pix), b21y = F(fb,1,1,pix);

        auto bil = [&](const float* base, int i, float fx, float fy, float* ox, float* oy) {
            float vx = (float)x + fx;
            float vy = (float)y + fy;
            float gx = 2.0f * vx / (float)(WW - 1) - 1.0f;
            float gy = 2.0f * vy / (float)(HH - 1) - 1.0f;
            float px = (gx + 1.0f) * 0.5f * (float)(WW - 1);
            float py = (gy + 1.0f) * 0.5f * (float)(HH - 1);
            px = fminf(fmaxf(px, 0.0f), (float)(WW - 1));
            py = fminf(fmaxf(py, 0.0f), (float)(HH - 1));
            float x0f = floorf(px), y0f = floorf(py);
            float wx1 = px - x0f, wx0 = 1.0f - wx1;
            float wy1 = py - y0f, wy0 = 1.0f - wy1;
            int xi0 = (int)x0f, yi0 = (int)y0f;
            int xc0 = min(max(xi0, 0), WW-1), xc1 = min(max(xi0+1, 0), WW-1);
            int yc0 = min(max(yi0, 0), HH-1), yc1 = min(max(yi0+1, 0), HH-1);
            float r[2];
            #pragma unroll
            for (int c = 0; c < 2; ++c) {
                float v00 = F(base, i, c, yc0*WW + xc0);
                float v10 = F(base, i, c, yc0*WW + xc1);
                float v01 = F(base, i, c, yc1*WW + xc0);
                float v11 = F(base, i, c, yc1*WW + xc1);
                r[c] = v00*(wx0*wy0) + v10*(wx1*wy0) + v01*(wx0*wy1) + v11*(wx1*wy1);
            }
            *ox = r[0]; *oy = r[1];
        };

        float wfx, wfy; bil(ff, 1, f01x, f01y, &wfx, &wfy);
        float f02x = f01x + wfx, f02y = f01y + wfy;
        float wbx, wby; bil(fb, 0, b21x, b21y, &wbx, &wby);
        float b20x = b21x + wbx, b20y = b21y + wby;

        float* A = addb + n * (3*HWP*6) + pix * 6;
        const int TS = HWP * 6;
        A[0] = 0.f;   A[1] = 0.f;   A[2] = f01x; A[3] = f01y; A[4] = f02x; A[5] = f02y;
        A[TS+0] = b10x; A[TS+1] = b10y; A[TS+2] = 0.f; A[TS+3] = 0.f; A[TS+4] = f12x; A[TS+5] = f12y;
        A[2*TS+0] = b20x; A[2*TS+1] = b20y; A[2*TS+2] = b21x; A[2*TS+3] = b21y; A[2*TS+4] = 0.f; A[2*TS+5] = 0.f;
    } else if (b < NB_FLOW + NB_WCVT) {
        int idx = (b - NB_FLOW) * 256 + tid;
        if (idx < WP0) {
            int oc = idx >> 8, ic = idx & 255;
            const float* sp = w_val + ((size_t)oc * 256 + ic) * 9;
            #pragma unroll
            for (int j = 0; j < 9; ++j)
                wfrag_store(Wb_val, 256, oc, ic, j, sp[j]);
        } else if (idx < WP0 + WP1) {
            int p3 = idx - WP0;
            int oc = p3 >> 8, ic = p3 & 255;
            const float* sp = (oc < 192)
                ? (w_off  + ((size_t)oc * 256 + ic) * 9)
                : (w_attn + ((size_t)(oc - 192) * 256 + ic) * 9);
            #pragma unroll
            for (int j = 0; j < 9; ++j)
                wfrag_store(Wb_oa, 288, oc, ic, j, sp[j]);
        } else {
            int p3 = idx - WP0 - WP1;
            int oc = p3 >> 8, ic = p3 & 255;
            const float* sp = w_out + ((size_t)oc * 256 + ic) * 9;
            #pragma unroll
            for (int j = 0; j < 9; ++j)
                wfrag_store(Wb_out, 256, oc, ic, j, sp[j]);
        }
    } else {
        int rem = b - NB_FLOW - NB_WCVT;
        int which = rem / 3456;
        int r2 = rem % 3456;
        int px0 = (r2 % 72) * 32;
        int ic0 = ((r2 / 72) % 8) * 32;
        int img = r2 / (72 * 8);
        const float* src = which ? query : inputf;
        unsigned short* dst = which ? inb_q : inb_v;
        #pragma unroll
        for (int s = 0; s < 4; ++s) {
            int icl = (tid >> 5) + s * 8, pxl = tid & 31;
            lds[icl][pxl] = src[((size_t)img * 256 + ic0 + icl) * HWP + px0 + pxl];
        }
        __syncthreads();
        #pragma unroll
        for (int s = 0; s < 4; ++s) {
            int pxl = (tid >> 5) + s * 8, icl = tid & 31;
            dst[((size_t)img * HWP + px0 + pxl) * 256 + ic0 + icl] = f2b(lds[icl][pxl]);
        }
    }
}

// ---------------------------------------------------------------------------
// Conv body: B from LDS slab (staged once per ic-chunk via gload_lds),
// A from GLOBAL fragment-major layout (coalesced, L2-hot). No per-tap
// barriers; compiler pipelines A-loads with its own vmcnt.
// ---------------------------------------------------------------------------
template<int NM>
__device__ __forceinline__ void conv_body(
    int cls, int s, int c_lo, int c_hi,
    const char* inIc, const char* WbF, int Mpad, int oc0, int pxb, int img,
    const float* bias_a, const float* bias_off, const float* bias_attn,
    unsigned short* Vout, float* offb, float* attnb, float* outp,
    const unsigned char* mask, char* lds)
{
    const int tid  = threadIdx.x;
    const int lane = tid & 63;
    const int wv   = tid >> 6;

    const int r0   = pxb / 48;
    const int rlo  = (r0 > 0) ? (r0 - 1) : 0;
    const int pxlo = rlo * 48;

    const int lrow8 = lane >> 3;
    const int lcol  = lane & 7;

    const int rowl = lane & 15;
    const int g    = lane >> 4;
    const int pxw  = pxb + (wv & 1) * 64;
    const int ob0  = (oc0 >> 4) + (wv >> 1) * NM;   // fragment-row base
    const int obn  = Mpad >> 4;                      // ob dimension size
    int ypx[4], xpx[4];
    #pragma unroll
    for (int p = 0; p < 4; ++p) {
        int px = pxw + p * 16 + rowl;
        ypx[p] = px / 48;
        xpx[p] = px % 48;
    }

    v4f acc[NM][4];
    #pragma unroll
    for (int m = 0; m < NM; ++m)
        #pragma unroll
        for (int p = 0; p < 4; ++p)
            #pragma unroll
            for (int e = 0; e < 4; ++e) acc[m][p][e] = 0.f;

    for (int c = c_lo; c < c_hi; ++c) {
        const int ic0b = c * 128;

        __syncthreads();   // all waves done reading previous slab
        #pragma unroll
        for (int rr = 0; rr < 9; ++rr) {
            int pe  = rr * 32 + wv * 8 + lrow8;
            int gpx = pxlo + pe;
            if (gpx > 2303) gpx = 2303;
            GLOAD_LDS16(inIc + (size_t)gpx * 512 + ic0b + ((lcol ^ (pe & 7)) << 4),
                        lds + (rr * 32 + wv * 8) * 128);
        }
        asm volatile("s_waitcnt vmcnt(0) lgkmcnt(0)" ::: "memory");
        __builtin_amdgcn_s_barrier();

        for (int k = 0; k < 9; ++k) {
            // A fragments: coalesced global loads (L2-hot), 2 kk-halves x NM
            const char* ak = WbF + ((size_t)(k * 4 + c) * obn) * 2048 + lane * 16;
            v8s a[NM][2];
            #pragma unroll
            for (int m = 0; m < NM; ++m)
                #pragma unroll
                for (int kk = 0; kk < 2; ++kk)
                    a[m][kk] = *(const v8s*)(ak + (size_t)((ob0 + m) * 2 + kk) * 1024);

            const int dy = k / 3 - 1, dx = k % 3 - 1;
            int bbase[4], bkey[4];
            #pragma unroll
            for (int p = 0; p < 4; ++p) {
                int ys = ypx[p] + dy, xs = xpx[p] + dx;
                bool val = ((unsigned)ys < 48u) && ((unsigned)xs < 48u);
                int pe = ys * 48 + xs - pxlo;
                bbase[p] = val ? (pe * 128) : LDS_ZROW;
                bkey[p]  = val ? ((pe & 7) << 4) : 0;
            }

            #pragma unroll
            for (int kk = 0; kk < 2; ++kk) {
                const int col = kk * 64 + g * 16;
                v8s bfr[4];
                #pragma unroll
                for (int p = 0; p < 4; ++p)
                    bfr[p] = *(const v8s*)(lds + bbase[p] + (col ^ bkey[p]));
                #pragma unroll
                for (int m = 0; m < NM; ++m)
                    #pragma unroll
                    for (int p = 0; p < 4; ++p)
                        acc[m][p] = __builtin_amdgcn_mfma_f32_16x16x32_bf16(a[m][kk], bfr[p], acc[m][p], 0, 0, 0);
            }
        }
    }

    // ---- epilogue ----
    const int n = img / T, t = img % T;
    const int ocw = oc0 + (wv >> 1) * (16 * NM);

    #pragma unroll
    for (int p = 0; p < 4; ++p) {
        const int px_f = pxw + p * 16 + rowl;
        const int q = t * HWP + px_f;
        bool mk = (cls == 0) ? (mask[n * LQ + q] != 0) : false;
        #pragma unroll
        for (int m = 0; m < NM; ++m) {
            const int oc_f = ocw + m * 16 + g * 4;
            if (cls == 0) {
                unsigned short o[4];
                #pragma unroll
                for (int r = 0; r < 4; ++r) {
                    float v = acc[m][p][r] + bias_a[oc_f + r];
                    if (mk) v = 0.f;
                    o[r] = f2b(v);
                }
                int head = oc_f >> 5, d0 = oc_f & 31;
                v2u pk;
                pk[0] = (unsigned)o[0] | ((unsigned)o[1] << 16);
                pk[1] = (unsigned)o[2] | ((unsigned)o[3] << 16);
                *(v2u*)(Vout + (((size_t)(t * BS + n) * NH + head) * HWP + px_f) * 32 + d0) = pk;
            } else if (cls == 1) {
                if (oc_f < 192) {
                    v4f v;
                    #pragma unroll
                    for (int r = 0; r < 4; ++r) v[r] = acc[m][p][r] + bias_off[oc_f + r];
                    *(v4f*)(offb + ((size_t)n * LQ + q) * 192 + oc_f) = v;
                } else {
                    v4f v;
                    #pragma unroll
                    for (int r = 0; r < 4; ++r) v[r] = acc[m][p][r] + bias_attn[oc_f - 192 + r];
                    *(v4f*)(attnb + ((size_t)n * LQ + q) * 96 + (oc_f - 192)) = v;
                }
            } else {
                // split-K half: exactly 2 atomic addends/elem -> deterministic
                #pragma unroll
                for (int r = 0; r < 4; ++r) {
                    float v = acc[m][p][r] + ((s == 0) ? bias_a[oc_f + r] : 0.f);
                    atomicAdd(&outp[((size_t)img * CCH + oc_f + r) * HWP + px_f], v);
                }
            }
        }
    }
}

// ---------------------------------------------------------------------------
// phase 0: physical [0,216) cls0 (NM=4), [216,540) cls1 (NM=3, oc0=mt*96),
// each class chunk-swizzled (locality + balance, r14).
// phase 1: split-K out conv: halves [0,216)/[216,432), each swizzled.
// ---------------------------------------------------------------------------
__global__ __launch_bounds__(256) void convbig(
    int phase,
    const unsigned short* __restrict__ in_a,
    const unsigned short* __restrict__ in_b,
    const unsigned short* __restrict__ Wb_a,
    const unsigned short* __restrict__ Wb_b,
    const float* __restrict__ bias_a,
    const float* __restrict__ bias_off,
    const float* __restrict__ bias_attn,
    unsigned short* __restrict__ Vout,
    float* __restrict__ offb,
    float* __restrict__ attnb,
    float* __restrict__ outp,
    const unsigned char* __restrict__ mask)
{
    __shared__ __align__(16) char lds[LDS_TOTAL];

    const int tid = threadIdx.x;
    if (tid < 8) {
        v8s z;
        #pragma unroll
        for (int j = 0; j < 8; ++j) z[j] = 0;
        *(v8s*)(lds + LDS_ZROW + tid * 16) = z;
    }

    const int p_phys = blockIdx.x;
    int b;
    if (p_phys < 216) b = xcd_swz(p_phys, 216);
    else if (phase == 0) b = 216 + xcd_swz(p_phys - 216, 324);
    else b = 216 + xcd_swz(p_phys - 216, 216);

    int cls, mt, nt, img, Mpad, c_lo, c_hi, s, oc0;
    const unsigned short *inb, *Wb;
    if (phase == 0) {
        s = 0; c_lo = 0; c_hi = 4;
        if (b < 216) { cls = 0; mt = b % 2; int r = b / 2; nt = r % 18; img = r / 18;
                       inb = in_a; Wb = Wb_a; Mpad = 256; oc0 = mt * 128; }
        else { b -= 216; cls = 1; mt = b % 3; int r = b / 3; nt = r % 18; img = r / 18;
               inb = in_b; Wb = Wb_b; Mpad = 288; oc0 = mt * 96; }
    } else {
        cls = 3; s = b / 216; b = b % 216;
        c_lo = 2 * s; c_hi = c_lo + 2;
        mt = b % 2; int r = b / 2; nt = r % 18; img = r / 18;
        inb = in_a; Wb = Wb_a; Mpad = 256; oc0 = mt * 128;
    }

    const int pxb = nt * 128;
    const char* inIc = (const char*)(inb + (size_t)img * HWP * 256);
    const char* WbFc = (const char*)Wb;

    if (cls == 1) {
        conv_body<3>(cls, s, c_lo, c_hi, inIc, WbFc, Mpad, oc0, pxb, img,
                     bias_a, bias_off, bias_attn, Vout, offb, attnb, outp, mask, lds);
    } else {
        conv_body<4>(cls, s, c_lo, c_hi, inIc, WbFc, Mpad, oc0, pxb, img,
                     bias_a, bias_off, bias_attn, Vout, offb, attnb, outp, mask, lds);
    }
}

// ---------------------------------------------------------------------------
// Deformable sampling (4-lane groups @64 VGPR, XCD-swizzled — PROVEN).
// ---------------------------------------------------------------------------
__global__ __launch_bounds__(256) void sample_kernel(
    const unsigned short* __restrict__ V,
    const float* __restrict__ offb,
    const float* __restrict__ attnb,
    const float* __restrict__ addb,
    const float* __restrict__ refp,
    unsigned short* __restrict__ midb)
{
    const int tid = threadIdx.x;
    const int gid = tid >> 2, li = tid & 3;
    const int lb = xcd_swz(blockIdx.x, (BS * LQ * NH) / 64);
    const int pair = lb * 64 + gid;
    const int head = pair & 7;
    const int nq = pair >> 3;
    const int n = nq / LQ, q = nq % LQ;
    const int t = q / HWP, pix = q % HWP;

    const float* al = attnb + ((size_t)n * LQ + q) * 96 + head * 12;
    float lg[12];
    {
        v4f t0 = *(const v4f*)al, t1 = *(const v4f*)(al + 4), t2 = *(const v4f*)(al + 8);
        #pragma unroll
        for (int j = 0; j < 4; ++j) { lg[j] = t0[j]; lg[4+j] = t1[j]; lg[8+j] = t2[j]; }
    }
    const float* ofp = offb + ((size_t)n * LQ + q) * 192 + head * 24;
    float of[24];
    #pragma unroll
    for (int j = 0; j < 6; ++j) {
        v4f v = *(const v4f*)(ofp + j * 4);
        #pragma unroll
        for (int e = 0; e < 4; ++e) of[j*4+e] = v[e];
    }
    const float* rpp = refp + ((size_t)n * LQ + q) * 6;
    const float* adp = addb + ((size_t)n * 3 * HWP + t * HWP + pix) * 6;
    float rp[6], ad[6];
    #pragma unroll
    for (int j = 0; j < 3; ++j) {
        v2f r = *(const v2f*)(rpp + j * 2);
        v2f a = *(const v2f*)(adp + j * 2);
        rp[j*2] = r[0]; rp[j*2+1] = r[1];
        ad[j*2] = a[0]; ad[j*2+1] = a[1];
    }

    float m = lg[0];
    #pragma unroll
    for (int j = 1; j < 12; ++j) m = fmaxf(m, lg[j]);
    float s = 0.f;
    #pragma unroll
    for (int j = 0; j < 12; ++j) { lg[j] = expf(lg[j] - m); s += lg[j]; }
    float inv = 1.0f / s;
    #pragma unroll
    for (int j = 0; j < 12; ++j) lg[j] *= inv;

    float acc[8];
    #pragma unroll
    for (int e = 0; e < 8; ++e) acc[e] = 0.f;

    #pragma unroll
    for (int l = 0; l < 3; ++l) {
        float refx = rp[l*2+0], refy = rp[l*2+1];
        float addx = ad[l*2+0], addy = ad[l*2+1];
        const unsigned short* Vi =
            V + (size_t)((l * BS + n) * NH + head) * HWP * DH + li * 8;
        #pragma unroll
        for (int p = 0; p < 4; ++p) {
            float ox = of[(l*4+p)*2+0] + addx;
            float oy = of[(l*4+p)*2+1] + addy;
            float locx = refx + ox * (1.0f/48.0f);
            float locy = refy + oy * (1.0f/48.0f);
            float gx = 2.0f*locx - 1.0f;
            float gy = 2.0f*locy - 1.0f;
            float pxf = ((gx + 1.0f) * 48.0f - 1.0f) * 0.5f;
            float pyf = ((gy + 1.0f) * 48.0f - 1.0f) * 0.5f;
            float x0f = floorf(pxf), y0f = floorf(pyf);
            float wx1 = pxf - x0f, wx0 = 1.0f - wx1;
            float wy1 = pyf - y0f, wy0 = 1.0f - wy1;
            int xi0 = (int)x0f, yi0 = (int)y0f;
            bool vx0 = (x0f >= 0.0f)     && (x0f <= 47.0f);
            bool vx1 = (x0f+1.f >= 0.0f) && (x0f+1.f <= 47.0f);
            bool vy0 = (y0f >= 0.0f)     && (y0f <= 47.0f);
            bool vy1 = (y0f+1.f >= 0.0f) && (y0f+1.f <= 47.0f);
            int xc0 = min(max(xi0, 0), 47),   xc1 = min(max(xi0+1, 0), 47);
            int yc0 = min(max(yi0, 0), 47),   yc1 = min(max(yi0+1, 0), 47);
            float aw = lg[l*4+p];
            float w00 = (vx0 && vy0) ? wx0*wy0*aw : 0.f;
            float w10 = (vx1 && vy0) ? wx1*wy0*aw : 0.f;
            float w01 = (vx0 && vy1) ? wx0*wy1*aw : 0.f;
            float w11 = (vx1 && vy1) ? wx1*wy1*aw : 0.f;
            v4u u00 = *(const v4u*)(Vi + (yc0*WW + xc0)*DH);
            v4u u10 = *(const v4u*)(Vi + (yc0*WW + xc1)*DH);
            v4u u01 = *(const v4u*)(Vi + (yc1*WW + xc0)*DH);
            v4u u11 = *(const v4u*)(Vi + (yc1*WW + xc1)*DH);
            #pragma unroll
            for (int cc = 0; cc < 4; ++cc) {
                v4u u = (cc == 0) ? u00 : (cc == 1) ? u10 : (cc == 2) ? u01 : u11;
                float w = (cc == 0) ? w00 : (cc == 1) ? w10 : (cc == 2) ? w01 : w11;
                #pragma unroll
                for (int e = 0; e < 4; ++e) {
                    acc[e*2+0] += w * __uint_as_float(u[e] << 16);
                    acc[e*2+1] += w * __uint_as_float(u[e] & 0xFFFF0000u);
                }
            }
        }
    }

    v4u pk;
    #pragma unroll
    for (int e = 0; e < 4; ++e)
        pk[e] = (unsigned)f2b(acc[e*2+0]) | ((unsigned)f2b(acc[e*2+1]) << 16);
    *(v4u*)(midb + ((size_t)(n * T + t) * HWP + pix) * 256 + head * 32 + li * 8) = pk;
}

// ---------------------------------------------------------------------------
extern "C" void kernel_launch(void* const* d_in, const int* in_sizes, int n_in,
                              void* d_out, int out_size, void* d_ws, size_t ws_size,
                              hipStream_t stream) {
    const float* query  = (const float*)d_in[0];
    const float* refp   = (const float*)d_in[1];
    const float* inputf = (const float*)d_in[2];
    const unsigned char* mask = (const unsigned char*)d_in[5];
    const float* ff     = (const float*)d_in[6];
    const float* fb     = (const float*)d_in[7];
    const float* w_off  = (const float*)d_in[8];
    const float* b_off  = (const float*)d_in[9];
    const float* w_attn = (const float*)d_in[10];
    const float* b_attn = (const float*)d_in[11];
    const float* w_val  = (const float*)d_in[12];
    const float* b_val  = (const float*)d_in[13];
    const float* w_out  = (const float*)d_in[14];
    const float* b_out  = (const float*)d_in[15];

    char* w = (char*)d_ws;
    float* offb  = (float*)w;           w += (size_t)BS*LQ*192*4;
    float* attnb = (float*)w;           w += (size_t)BS*LQ*96*4;
    float* addb  = (float*)w;           w += (size_t)BS*3*HWP*6*4;
    unsigned short* V      = (unsigned short*)w; w += (size_t)48*HWP*DH*2;
    unsigned short* inb_q  = (unsigned short*)w; w += (size_t)NIMG*HWP*256*2;
    unsigned short* inb_v  = (unsigned short*)w; w += (size_t)NIMG*HWP*256*2;
    unsigned short* midb   = inb_v;  // alias: value conv done reading before sampler writes
    unsigned short* Wb_val = (unsigned short*)w; w += (size_t)9*256*256*2;
    unsigned short* Wb_oa  = (unsigned short*)w; w += (size_t)9*288*256*2;
    unsigned short* Wb_out = (unsigned short*)w; w += (size_t)9*256*256*2;
    float* outp = (float*)d_out;

    hipMemsetAsync(outp, 0, (size_t)NIMG * CCH * HWP * 4, stream);

    prep_kernel<<<NB_FLOW + NB_WCVT + NB_TCVT, 256, 0, stream>>>(
        ff, fb, addb, w_val, w_off, w_attn, w_out,
        Wb_val, Wb_oa, Wb_out, inputf, query, inb_v, inb_q);

    convbig<<<540, 256, 0, stream>>>(0, inb_v, inb_q, Wb_val, Wb_oa,
                                     b_val, b_off, b_attn,
                                     V, offb, attnb, nullptr, mask);

    sample_kernel<<<(BS*LQ*NH)/64, 256, 0, stream>>>(V, offb, attnb, addb, refp, midb);

    convbig<<<432, 256, 0, stream>>>(1, midb, nullptr, Wb_out, nullptr,
                                     b_out, nullptr, nullptr,
                                     nullptr, nullptr, nullptr, outp, nullptr);
}

// Round 17
// 139.457 us; speedup vs baseline: 1.6810x; 1.6810x over previous
//
#include <hip/hip_runtime.h>
#include <hip/hip_bf16.h>

#define BS   2
#define T    3
#define CCH  256
#define HH   48
#define WW   48
#define NH   8
#define NP   4
#define NL   3
#define DH   32
#define HWP  (HH*WW)     // 2304
#define LQ   (T*HWP)     // 6912
#define NIMG (BS*T)      // 6

typedef short v8s __attribute__((ext_vector_type(8)));
typedef float v4f __attribute__((ext_vector_type(4)));
typedef float v2f __attribute__((ext_vector_type(2)));
typedef unsigned int v2u __attribute__((ext_vector_type(2)));
typedef unsigned int v4u __attribute__((ext_vector_type(4)));

__device__ __forceinline__ unsigned short f2b(float f) {
    unsigned u = __float_as_uint(f);
    return (unsigned short)((u + 0x7FFFu + ((u >> 16) & 1u)) >> 16);
}

#define GLOAD_LDS16(gp, lp) \
    __builtin_amdgcn_global_load_lds((const __attribute__((address_space(1))) unsigned int*)(const void*)(gp), \
                                     (__attribute__((address_space(3))) unsigned int*)(void*)(lp), 16, 0, 0)

// LDS layout (bytes): Abuf0 @0 (16K), Abuf1 @16384, slab @32768 (288*128=36864),
// zero-row @69632 (128). Total 69760 -> 2 blocks/CU.
// Ledger (conv inner-loop mutations, ALL regressed):
//   r6  single-buffer A -> serialized tap loads        (72 -> 118 us)
//   r8  reg-prefetch + ds_write on barrier path        (74 -> 87)
//   r10 wide 4x6 tile -> VGPR 96->188, occupancy halved (74 -> 100)
//   r16 A-from-global -> un-pipelined L2 latency per tap, VGPR 132 (62->116)
// r12 2-lane sampler -> VGPR 256 (sample 25->76). PROVEN optima:
//   conv    = 64oc x 64px wave tile, A-dbuf + vmcnt(NM), @96 VGPR
//   sampler = 4-lane groups @64 VGPR
//   + per-class XCD swizzle (r14), sampler XCD swizzle (r15),
//     NM=3 for off+attn (r11), atomic split-K phase-1 (r9).
// This is the r15 configuration — the measured structural plateau.
#define LDS_SLAB  32768
#define LDS_ZROW  69632
#define LDS_TOTAL 69760

// m204 bijective chunked swizzle within a range of n blocks.
__device__ __forceinline__ int xcd_swz(int p, int n) {
    int q = n >> 3, r = n & 7;
    int xcd = p & 7, j = p >> 3;
    return (xcd < r ? xcd * (q + 1) : r * (q + 1) + (xcd - r) * q) + j;
}

// ---------------------------------------------------------------------------
// Fused prep kernel: range-partitioned grid.
//   [0,18)         flow -> addb
//   [18,818)       weight cvt, one thread per (oc,ic): 9 contiguous f32 reads
//   [818,818+6912) input cvt (32x32 LDS transpose)
// ---------------------------------------------------------------------------
#define NB_FLOW 18
#define NB_WCVT 800
#define NB_TCVT 6912
#define WP0 (256*256)
#define WP1 (288*256)

__global__ __launch_bounds__(256) void prep_kernel(
    const float* __restrict__ ff, const float* __restrict__ fb,
    float* __restrict__ addb,
    const float* __restrict__ w_val, const float* __restrict__ w_off,
    const float* __restrict__ w_attn, const float* __restrict__ w_out,
    unsigned short* __restrict__ Wb_val, unsigned short* __restrict__ Wb_oa,
    unsigned short* __restrict__ Wb_out,
    const float* __restrict__ inputf, const float* __restrict__ query,
    unsigned short* __restrict__ inb_v, unsigned short* __restrict__ inb_q)
{
    __shared__ float lds[32][33];
    const int b = blockIdx.x;
    const int tid = threadIdx.x;

    if (b < NB_FLOW) {
        int idx = b * 256 + tid;
        int n = idx / HWP, pix = idx % HWP;
        int y = pix / WW, x = pix % WW;

        auto F = [&](const float* base, int i, int c, int p) {
            return base[n * (2*2*HWP) + i * (2*HWP) + c * HWP + p];
        };

        float f01x = F(ff,0,0,pix), f01y = F(ff,0,1,pix);
        float f12x = F(ff,1,0,pix), f12y = F(ff,1,1,pix);
        float b10x = F(fb,0,0,pix), b10y = F(fb,0,1,pix);
        float b21x = F(fb,1,0,pix), b21y = F(fb,1,1,pix);

        auto bil = [&](const float* base, int i, float fx, float fy, float* ox, float* oy) {
            float vx = (float)x + fx;
            float vy = (float)y + fy;
            float gx = 2.0f * vx / (float)(WW - 1) - 1.0f;
            float gy = 2.0f * vy / (float)(HH - 1) - 1.0f;
            float px = (gx + 1.0f) * 0.5f * (float)(WW - 1);
            float py = (gy + 1.0f) * 0.5f * (float)(HH - 1);
            px = fminf(fmaxf(px, 0.0f), (float)(WW - 1));
            py = fminf(fmaxf(py, 0.0f), (float)(HH - 1));
            float x0f = floorf(px), y0f = floorf(py);
            float wx1 = px - x0f, wx0 = 1.0f - wx1;
            float wy1 = py - y0f, wy0 = 1.0f - wy1;
            int xi0 = (int)x0f, yi0 = (int)y0f;
            int xc0 = min(max(xi0, 0), WW-1), xc1 = min(max(xi0+1, 0), WW-1);
            int yc0 = min(max(yi0, 0), HH-1), yc1 = min(max(yi0+1, 0), HH-1);
            float r[2];
            #pragma unroll
            for (int c = 0; c < 2; ++c) {
                float v00 = F(base, i, c, yc0*WW + xc0);
                float v10 = F(base, i, c, yc0*WW + xc1);
                float v01 = F(base, i, c, yc1*WW + xc0);
                float v11 = F(base, i, c, yc1*WW + xc1);
                r[c] = v00*(wx0*wy0) + v10*(wx1*wy0) + v01*(wx0*wy1) + v11*(wx1*wy1);
            }
            *ox = r[0]; *oy = r[1];
        };

        float wfx, wfy; bil(ff, 1, f01x, f01y, &wfx, &wfy);
        float f02x = f01x + wfx, f02y = f01y + wfy;
        float wbx, wby; bil(fb, 0, b21x, b21y, &wbx, &wby);
        float b20x = b21x + wbx, b20y = b21y + wby;

        float* A = addb + n * (3*HWP*6) + pix * 6;
        const int TS = HWP * 6;
        A[0] = 0.f;   A[1] = 0.f;   A[2] = f01x; A[3] = f01y; A[4] = f02x; A[5] = f02y;
        A[TS+0] = b10x; A[TS+1] = b10y; A[TS+2] = 0.f; A[TS+3] = 0.f; A[TS+4] = f12x; A[TS+5] = f12y;
        A[2*TS+0] = b20x; A[2*TS+1] = b20y; A[2*TS+2] = b21x; A[2*TS+3] = b21y; A[2*TS+4] = 0.f; A[2*TS+5] = 0.f;
    } else if (b < NB_FLOW + NB_WCVT) {
        // one thread per (oc,ic): read 9 contiguous f32, write 9 bf16 planes
        int idx = (b - NB_FLOW) * 256 + tid;
        if (idx < WP0) {
            int oc = idx >> 8, ic = idx & 255;
            const float* sp = w_val + ((size_t)oc * 256 + ic) * 9;
            #pragma unroll
            for (int j = 0; j < 9; ++j)
                Wb_val[(size_t)j * WP0 + oc * 256 + ic] = f2b(sp[j]);
        } else if (idx < WP0 + WP1) {
            int p3 = idx - WP0;
            int oc = p3 >> 8, ic = p3 & 255;
            const float* sp = (oc < 192)
                ? (w_off  + ((size_t)oc * 256 + ic) * 9)
                : (w_attn + ((size_t)(oc - 192) * 256 + ic) * 9);
            #pragma unroll
            for (int j = 0; j < 9; ++j)
                Wb_oa[(size_t)j * WP1 + oc * 256 + ic] = f2b(sp[j]);
        } else {
            int p3 = idx - WP0 - WP1;
            int oc = p3 >> 8, ic = p3 & 255;
            const float* sp = w_out + ((size_t)oc * 256 + ic) * 9;
            #pragma unroll
            for (int j = 0; j < 9; ++j)
                Wb_out[(size_t)j * WP0 + oc * 256 + ic] = f2b(sp[j]);
        }
    } else {
        int rem = b - NB_FLOW - NB_WCVT;
        int which = rem / 3456;
        int r2 = rem % 3456;
        int px0 = (r2 % 72) * 32;
        int ic0 = ((r2 / 72) % 8) * 32;
        int img = r2 / (72 * 8);
        const float* src = which ? query : inputf;
        unsigned short* dst = which ? inb_q : inb_v;
        #pragma unroll
        for (int s = 0; s < 4; ++s) {
            int icl = (tid >> 5) + s * 8, pxl = tid & 31;
            lds[icl][pxl] = src[((size_t)img * 256 + ic0 + icl) * HWP + px0 + pxl];
        }
        __syncthreads();
        #pragma unroll
        for (int s = 0; s < 4; ++s) {
            int pxl = (tid >> 5) + s * 8, icl = tid & 31;
            dst[((size_t)img * HWP + px0 + pxl) * 256 + ic0 + icl] = f2b(lds[icl][pxl]);
        }
    }
}

// ---------------------------------------------------------------------------
// r11 conv body (NM = A-fragments per wave; 4 -> 128-oc, 3 -> 96-oc block).
// Schedule r7/r9 verbatim: slab once/ic-chunk, 9 taps A-dbuf + vmcnt(NM).
// ---------------------------------------------------------------------------
template<int NM>
__device__ __forceinline__ void conv_body(
    int cls, int s, int c_lo, int c_hi,
    const char* inIc, const char* Wbc, int Mpad, int oc0, int pxb, int img,
    const float* bias_a, const float* bias_off, const float* bias_attn,
    unsigned short* Vout, float* offb, float* attnb, float* outp,
    const unsigned char* mask, char* lds)
{
    const int tid  = threadIdx.x;
    const int lane = tid & 63;
    const int wv   = tid >> 6;

    const int r0   = pxb / 48;
    const int rlo  = (r0 > 0) ? (r0 - 1) : 0;
    const int pxlo = rlo * 48;

    const int lrow8 = lane >> 3;
    const int lcol  = lane & 7;

    const int rowl = lane & 15;
    const int g    = lane >> 4;
    const int keyx = (rowl & 7) << 4;
    const int aoff0 = ((wv >> 1) * (16 * NM) + rowl) * 128;
    const int pxw   = pxb + (wv & 1) * 64;
    int ypx[4], xpx[4];
    #pragma unroll
    for (int p = 0; p < 4; ++p) {
        int px = pxw + p * 16 + rowl;
        ypx[p] = px / 48;
        xpx[p] = px % 48;
    }
    int ocr_[NM];
    #pragma unroll
    for (int j = 0; j < NM; ++j) ocr_[j] = j * 32 + wv * 8 + lrow8;

    v4f acc[NM][4];
    #pragma unroll
    for (int m = 0; m < NM; ++m)
        #pragma unroll
        for (int p = 0; p < 4; ++p)
            #pragma unroll
            for (int e = 0; e < 4; ++e) acc[m][p][e] = 0.f;

    for (int c = c_lo; c < c_hi; ++c) {
        const int ic0b = c * 128;

        #pragma unroll
        for (int rr = 0; rr < 9; ++rr) {
            int pe  = rr * 32 + wv * 8 + lrow8;
            int gpx = pxlo + pe;
            if (gpx > 2303) gpx = 2303;
            GLOAD_LDS16(inIc + (size_t)gpx * 512 + ic0b + ((lcol ^ (pe & 7)) << 4),
                        lds + LDS_SLAB + (rr * 32 + wv * 8) * 128);
        }
        #pragma unroll
        for (int j = 0; j < NM; ++j) {
            GLOAD_LDS16(Wbc + (size_t)(oc0 + ocr_[j]) * 512 + ic0b + ((lcol ^ (ocr_[j] & 7)) << 4),
                        lds + (j * 32 + wv * 8) * 128);
        }
        asm volatile("s_waitcnt vmcnt(0) lgkmcnt(0)" ::: "memory");
        __builtin_amdgcn_s_barrier();

        for (int k = 0; k < 9; ++k) {
            const int dy = k / 3 - 1, dx = k % 3 - 1;
            const int cur = k & 1;
            if (k < 8) {
                const char* wk1 = Wbc + (size_t)(k + 1) * Mpad * 512;
                #pragma unroll
                for (int j = 0; j < NM; ++j) {
                    GLOAD_LDS16(wk1 + (size_t)(oc0 + ocr_[j]) * 512 + ic0b + ((lcol ^ (ocr_[j] & 7)) << 4),
                                lds + (cur ^ 1) * 16384 + (j * 32 + wv * 8) * 128);
                }
                if (NM == 4) { asm volatile("s_waitcnt vmcnt(4)" ::: "memory"); }
                else         { asm volatile("s_waitcnt vmcnt(3)" ::: "memory"); }
            } else {
                asm volatile("s_waitcnt vmcnt(0)" ::: "memory");
            }
            __builtin_amdgcn_s_barrier();

            int bbase[4], bkey[4];
            #pragma unroll
            for (int p = 0; p < 4; ++p) {
                int ys = ypx[p] + dy, xs = xpx[p] + dx;
                bool val = ((unsigned)ys < 48u) && ((unsigned)xs < 48u);
                int pe = ys * 48 + xs - pxlo;
                bbase[p] = val ? (LDS_SLAB + pe * 128) : LDS_ZROW;
                bkey[p]  = val ? ((pe & 7) << 4) : 0;
            }

            #pragma unroll
            for (int kk = 0; kk < 2; ++kk) {
                const int col = kk * 64 + g * 16;
                v8s a[NM], bfr[4];
                #pragma unroll
                for (int m = 0; m < NM; ++m)
                    a[m] = *(const v8s*)(lds + cur * 16384 + aoff0 + m * 2048 + (col ^ keyx));
                #pragma unroll
                for (int p = 0; p < 4; ++p)
                    bfr[p] = *(const v8s*)(lds + bbase[p] + (col ^ bkey[p]));
                #pragma unroll
                for (int m = 0; m < NM; ++m)
                    #pragma unroll
                    for (int p = 0; p < 4; ++p)
                        acc[m][p] = __builtin_amdgcn_mfma_f32_16x16x32_bf16(a[m], bfr[p], acc[m][p], 0, 0, 0);
            }
            __builtin_amdgcn_s_barrier();
        }
    }

    // ---- epilogue ----
    const int n = img / T, t = img % T;
    const int ocw = oc0 + (wv >> 1) * (16 * NM);

    #pragma unroll
    for (int p = 0; p < 4; ++p) {
        const int px_f = pxw + p * 16 + rowl;
        const int q = t * HWP + px_f;
        bool mk = (cls == 0) ? (mask[n * LQ + q] != 0) : false;
        #pragma unroll
        for (int m = 0; m < NM; ++m) {
            const int oc_f = ocw + m * 16 + g * 4;
            if (cls == 0) {
                unsigned short o[4];
                #pragma unroll
                for (int r = 0; r < 4; ++r) {
                    float v = acc[m][p][r] + bias_a[oc_f + r];
                    if (mk) v = 0.f;
                    o[r] = f2b(v);
                }
                int head = oc_f >> 5, d0 = oc_f & 31;
                v2u pk;
                pk[0] = (unsigned)o[0] | ((unsigned)o[1] << 16);
                pk[1] = (unsigned)o[2] | ((unsigned)o[3] << 16);
                *(v2u*)(Vout + (((size_t)(t * BS + n) * NH + head) * HWP + px_f) * 32 + d0) = pk;
            } else if (cls == 1) {
                if (oc_f < 192) {
                    v4f v;
                    #pragma unroll
                    for (int r = 0; r < 4; ++r) v[r] = acc[m][p][r] + bias_off[oc_f + r];
                    *(v4f*)(offb + ((size_t)n * LQ + q) * 192 + oc_f) = v;
                } else {
                    v4f v;
                    #pragma unroll
                    for (int r = 0; r < 4; ++r) v[r] = acc[m][p][r] + bias_attn[oc_f - 192 + r];
                    *(v4f*)(attnb + ((size_t)n * LQ + q) * 96 + (oc_f - 192)) = v;
                }
            } else {
                // split-K half: exactly 2 atomic addends/elem -> deterministic
                #pragma unroll
                for (int r = 0; r < 4; ++r) {
                    float v = acc[m][p][r] + ((s == 0) ? bias_a[oc_f + r] : 0.f);
                    atomicAdd(&outp[((size_t)img * CCH + oc_f + r) * HWP + px_f], v);
                }
            }
        }
    }
}

// ---------------------------------------------------------------------------
// phase 0: physical [0,216) -> cls0 (NM=4), swizzled within class;
//          physical [216,540) -> cls1 (NM=3, oc0=mt*96), swizzled within class.
// phase 1: split-K out conv, physical [0,216) s=0 / [216,432) s=1, each half
//          swizzled within itself.
// ---------------------------------------------------------------------------
__global__ __launch_bounds__(256) void convbig(
    int phase,
    const unsigned short* __restrict__ in_a,
    const unsigned short* __restrict__ in_b,
    const unsigned short* __restrict__ Wb_a,
    const unsigned short* __restrict__ Wb_b,
    const float* __restrict__ bias_a,
    const float* __restrict__ bias_off,
    const float* __restrict__ bias_attn,
    unsigned short* __restrict__ Vout,
    float* __restrict__ offb,
    float* __restrict__ attnb,
    float* __restrict__ outp,
    const unsigned char* __restrict__ mask)
{
    __shared__ __align__(16) char lds[LDS_TOTAL];

    const int tid = threadIdx.x;
    if (tid < 8) {
        v8s z;
        #pragma unroll
        for (int j = 0; j < 8; ++j) z[j] = 0;
        *(v8s*)(lds + LDS_ZROW + tid * 16) = z;
    }

    const int p_phys = blockIdx.x;
    int b;
    if (p_phys < 216) b = xcd_swz(p_phys, 216);
    else if (phase == 0) b = 216 + xcd_swz(p_phys - 216, 324);
    else b = 216 + xcd_swz(p_phys - 216, 216);

    int cls, mt, nt, img, Mpad, c_lo, c_hi, s, oc0;
    const unsigned short *inb, *Wb;
    if (phase == 0) {
        s = 0; c_lo = 0; c_hi = 4;
        if (b < 216) { cls = 0; mt = b % 2; int r = b / 2; nt = r % 18; img = r / 18;
                       inb = in_a; Wb = Wb_a; Mpad = 256; oc0 = mt * 128; }
        else { b -= 216; cls = 1; mt = b % 3; int r = b / 3; nt = r % 18; img = r / 18;
               inb = in_b; Wb = Wb_b; Mpad = 288; oc0 = mt * 96; }
    } else {
        cls = 3; s = b / 216; b = b % 216;
        c_lo = 2 * s; c_hi = c_lo + 2;
        mt = b % 2; int r = b / 2; nt = r % 18; img = r / 18;
        inb = in_a; Wb = Wb_a; Mpad = 256; oc0 = mt * 128;
    }

    const int pxb = nt * 128;
    const char* inIc = (const char*)(inb + (size_t)img * HWP * 256);
    const char* Wbc  = (const char*)Wb;

    if (cls == 1) {
        conv_body<3>(cls, s, c_lo, c_hi, inIc, Wbc, Mpad, oc0, pxb, img,
                     bias_a, bias_off, bias_attn, Vout, offb, attnb, outp, mask, lds);
    } else {
        conv_body<4>(cls, s, c_lo, c_hi, inIc, Wbc, Mpad, oc0, pxb, img,
                     bias_a, bias_off, bias_attn, Vout, offb, attnb, outp, mask, lds);
    }
}

// ---------------------------------------------------------------------------
// Deformable sampling (4-lane groups @64 VGPR, XCD-swizzled — PROVEN).
// ---------------------------------------------------------------------------
__global__ __launch_bounds__(256) void sample_kernel(
    const unsigned short* __restrict__ V,
    const float* __restrict__ offb,
    const float* __restrict__ attnb,
    const float* __restrict__ addb,
    const float* __restrict__ refp,
    unsigned short* __restrict__ midb)
{
    const int tid = threadIdx.x;
    const int gid = tid >> 2, li = tid & 3;
    const int lb = xcd_swz(blockIdx.x, (BS * LQ * NH) / 64);
    const int pair = lb * 64 + gid;
    const int head = pair & 7;
    const int nq = pair >> 3;
    const int n = nq / LQ, q = nq % LQ;
    const int t = q / HWP, pix = q % HWP;

    const float* al = attnb + ((size_t)n * LQ + q) * 96 + head * 12;
    float lg[12];
    {
        v4f t0 = *(const v4f*)al, t1 = *(const v4f*)(al + 4), t2 = *(const v4f*)(al + 8);
        #pragma unroll
        for (int j = 0; j < 4; ++j) { lg[j] = t0[j]; lg[4+j] = t1[j]; lg[8+j] = t2[j]; }
    }
    const float* ofp = offb + ((size_t)n * LQ + q) * 192 + head * 24;
    float of[24];
    #pragma unroll
    for (int j = 0; j < 6; ++j) {
        v4f v = *(const v4f*)(ofp + j * 4);
        #pragma unroll
        for (int e = 0; e < 4; ++e) of[j*4+e] = v[e];
    }
    const float* rpp = refp + ((size_t)n * LQ + q) * 6;
    const float* adp = addb + ((size_t)n * 3 * HWP + t * HWP + pix) * 6;
    float rp[6], ad[6];
    #pragma unroll
    for (int j = 0; j < 3; ++j) {
        v2f r = *(const v2f*)(rpp + j * 2);
        v2f a = *(const v2f*)(adp + j * 2);
        rp[j*2] = r[0]; rp[j*2+1] = r[1];
        ad[j*2] = a[0]; ad[j*2+1] = a[1];
    }

    float m = lg[0];
    #pragma unroll
    for (int j = 1; j < 12; ++j) m = fmaxf(m, lg[j]);
    float s = 0.f;
    #pragma unroll
    for (int j = 0; j < 12; ++j) { lg[j] = expf(lg[j] - m); s += lg[j]; }
    float inv = 1.0f / s;
    #pragma unroll
    for (int j = 0; j < 12; ++j) lg[j] *= inv;

    float acc[8];
    #pragma unroll
    for (int e = 0; e < 8; ++e) acc[e] = 0.f;

    #pragma unroll
    for (int l = 0; l < 3; ++l) {
        float refx = rp[l*2+0], refy = rp[l*2+1];
        float addx = ad[l*2+0], addy = ad[l*2+1];
        const unsigned short* Vi =
            V + (size_t)((l * BS + n) * NH + head) * HWP * DH + li * 8;
        #pragma unroll
        for (int p = 0; p < 4; ++p) {
            float ox = of[(l*4+p)*2+0] + addx;
            float oy = of[(l*4+p)*2+1] + addy;
            float locx = refx + ox * (1.0f/48.0f);
            float locy = refy + oy * (1.0f/48.0f);
            float gx = 2.0f*locx - 1.0f;
            float gy = 2.0f*locy - 1.0f;
            float pxf = ((gx + 1.0f) * 48.0f - 1.0f) * 0.5f;
            float pyf = ((gy + 1.0f) * 48.0f - 1.0f) * 0.5f;
            float x0f = floorf(pxf), y0f = floorf(pyf);
            float wx1 = pxf - x0f, wx0 = 1.0f - wx1;
            float wy1 = pyf - y0f, wy0 = 1.0f - wy1;
            int xi0 = (int)x0f, yi0 = (int)y0f;
            bool vx0 = (x0f >= 0.0f)     && (x0f <= 47.0f);
            bool vx1 = (x0f+1.f >= 0.0f) && (x0f+1.f <= 47.0f);
            bool vy0 = (y0f >= 0.0f)     && (y0f <= 47.0f);
            bool vy1 = (y0f+1.f >= 0.0f) && (y0f+1.f <= 47.0f);
            int xc0 = min(max(xi0, 0), 47),   xc1 = min(max(xi0+1, 0), 47);
            int yc0 = min(max(yi0, 0), 47),   yc1 = min(max(yi0+1, 0), 47);
            float aw = lg[l*4+p];
            float w00 = (vx0 && vy0) ? wx0*wy0*aw : 0.f;
            float w10 = (vx1 && vy0) ? wx1*wy0*aw : 0.f;
            float w01 = (vx0 && vy1) ? wx0*wy1*aw : 0.f;
            float w11 = (vx1 && vy1) ? wx1*wy1*aw : 0.f;
            v4u u00 = *(const v4u*)(Vi + (yc0*WW + xc0)*DH);
            v4u u10 = *(const v4u*)(Vi + (yc0*WW + xc1)*DH);
            v4u u01 = *(const v4u*)(Vi + (yc1*WW + xc0)*DH);
            v4u u11 = *(const v4u*)(Vi + (yc1*WW + xc1)*DH);
            #pragma unroll
            for (int cc = 0; cc < 4; ++cc) {
                v4u u = (cc == 0) ? u00 : (cc == 1) ? u10 : (cc == 2) ? u01 : u11;
                float w = (cc == 0) ? w00 : (cc == 1) ? w10 : (cc == 2) ? w01 : w11;
                #pragma unroll
                for (int e = 0; e < 4; ++e) {
                    acc[e*2+0] += w * __uint_as_float(u[e] << 16);
                    acc[e*2+1] += w * __uint_as_float(u[e] & 0xFFFF0000u);
                }
            }
        }
    }

    v4u pk;
    #pragma unroll
    for (int e = 0; e < 4; ++e)
        pk[e] = (unsigned)f2b(acc[e*2+0]) | ((unsigned)f2b(acc[e*2+1]) << 16);
    *(v4u*)(midb + ((size_t)(n * T + t) * HWP + pix) * 256 + head * 32 + li * 8) = pk;
}

// ---------------------------------------------------------------------------
extern "C" void kernel_launch(void* const* d_in, const int* in_sizes, int n_in,
                              void* d_out, int out_size, void* d_ws, size_t ws_size,
                              hipStream_t stream) {
    const float* query  = (const float*)d_in[0];
    const float* refp   = (const float*)d_in[1];
    const float* inputf = (const float*)d_in[2];
    const unsigned char* mask = (const unsigned char*)d_in[5];
    const float* ff     = (const float*)d_in[6];
    const float* fb     = (const float*)d_in[7];
    const float* w_off  = (const float*)d_in[8];
    const float* b_off  = (const float*)d_in[9];
    const float* w_attn = (const float*)d_in[10];
    const float* b_attn = (const float*)d_in[11];
    const float* w_val  = (const float*)d_in[12];
    const float* b_val  = (const float*)d_in[13];
    const float* w_out  = (const float*)d_in[14];
    const float* b_out  = (const float*)d_in[15];

    char* w = (char*)d_ws;
    float* offb  = (float*)w;           w += (size_t)BS*LQ*192*4;
    float* attnb = (float*)w;           w += (size_t)BS*LQ*96*4;
    float* addb  = (float*)w;           w += (size_t)BS*3*HWP*6*4;
    unsigned short* V      = (unsigned short*)w; w += (size_t)48*HWP*DH*2;
    unsigned short* inb_q  = (unsigned short*)w; w += (size_t)NIMG*HWP*256*2;
    unsigned short* inb_v  = (unsigned short*)w; w += (size_t)NIMG*HWP*256*2;
    unsigned short* midb   = inb_v;  // alias: value conv done reading before sampler writes
    unsigned short* Wb_val = (unsigned short*)w; w += (size_t)9*256*256*2;
    unsigned short* Wb_oa  = (unsigned short*)w; w += (size_t)9*288*256*2;
    unsigned short* Wb_out = (unsigned short*)w; w += (size_t)9*256*256*2;
    float* outp = (float*)d_out;

    hipMemsetAsync(outp, 0, (size_t)NIMG * CCH * HWP * 4, stream);

    prep_kernel<<<NB_FLOW + NB_WCVT + NB_TCVT, 256, 0, stream>>>(
        ff, fb, addb, w_val, w_off, w_attn, w_out,
        Wb_val, Wb_oa, Wb_out, inputf, query, inb_v, inb_q);

    convbig<<<540, 256, 0, stream>>>(0, inb_v, inb_q, Wb_val, Wb_oa,
                                     b_val, b_off, b_attn,
                                     V, offb, attnb, nullptr, mask);

    sample_kernel<<<(BS*LQ*NH)/64, 256, 0, stream>>>(V, offb, attnb, addb, refp, midb);

    convbig<<<432, 256, 0, stream>>>(1, midb, nullptr, Wb_out, nullptr,
                                     b_out, nullptr, nullptr,
                                     nullptr, nullptr, nullptr, outp, nullptr);
}